// Round 1
// baseline (631.572 us; speedup 1.0000x reference)
//
#include <hip/hip_runtime.h>
#include <cstdint>
#include <cstddef>

using u16 = unsigned short;
typedef __bf16 bf16x8 __attribute__((ext_vector_type(8)));
typedef float f32x4 __attribute__((ext_vector_type(4)));

#define T_TOK 4096
#define HDIM 1024
#define EXP 8
#define IDIM 4096
#define NROWS 8192      // T_TOK * 2, exact (top-2 always selects 2 distinct experts)
#define PAD_ROWS 8320   // +128 so last-tile OOB row reads stay inside ws
#define BM 128
#define BN 128
#define BK 64
#define MAX_TILES 72    // sum ceil(n_e/128) <= 64 + 7

__device__ __forceinline__ u16 f2bf(float f) {
  union { float f; uint32_t u; } v; v.f = f;
  uint32_t u = v.u;
  u += 0x7fffu + ((u >> 16) & 1u);   // RNE
  return (u16)(u >> 16);
}

__device__ __forceinline__ void async_copy16(const u16* g, u16* s) {
  __builtin_amdgcn_global_load_lds((__attribute__((address_space(1))) void*)(void*)g,
                                   (__attribute__((address_space(3))) void*)s, 16, 0, 0);
}

// ---------------- gating: fp32 logits, softmax/top-2/renorm -----------------
__global__ __launch_bounds__(256) void gate_kernel(const float* __restrict__ x,
                                                   const float* __restrict__ Wg,
                                                   int* __restrict__ sel_e,
                                                   float* __restrict__ sel_w) {
  int lane = threadIdx.x & 63;
  int wave = threadIdx.x >> 6;
  int t = blockIdx.x * 4 + wave;
  const float* xr = x + (size_t)t * HDIM;
  float p[8];
#pragma unroll
  for (int e = 0; e < 8; ++e) p[e] = 0.f;
#pragma unroll
  for (int i = 0; i < 16; ++i) {
    int h = i * 64 + lane;
    float xv = xr[h];
    const float4* w4 = (const float4*)(Wg + h * 8);
    float4 a = w4[0], b = w4[1];
    p[0] += xv * a.x; p[1] += xv * a.y; p[2] += xv * a.z; p[3] += xv * a.w;
    p[4] += xv * b.x; p[5] += xv * b.y; p[6] += xv * b.z; p[7] += xv * b.w;
  }
#pragma unroll
  for (int e = 0; e < 8; ++e) {
#pragma unroll
    for (int off = 32; off > 0; off >>= 1) p[e] += __shfl_xor(p[e], off);
  }
  if (lane == 0) {
    int e0 = 0; float m0 = p[0];
#pragma unroll
    for (int e = 1; e < 8; ++e) { if (p[e] > m0) { m0 = p[e]; e0 = e; } }
    int e1 = -1; float m1 = -3.4e38f;
#pragma unroll
    for (int e = 0; e < 8; ++e) { if (e != e0 && p[e] > m1) { m1 = p[e]; e1 = e; } }
    // renormalized top-2 softmax: denominator cancels
    float r = expf(m1 - m0);
    float w0 = 1.f / (1.f + r);
    float w1 = r / (1.f + r);
    sel_e[2 * t] = e0; sel_e[2 * t + 1] = e1;
    sel_w[2 * t] = w0; sel_w[2 * t + 1] = w1;
  }
}

// ---------------- routing: counting sort + tile descriptors -----------------
__global__ void route_kernel(const int* __restrict__ sel_e, const float* __restrict__ sel_w,
                             int* __restrict__ row_token, float* __restrict__ row_weight,
                             int* __restrict__ tile_e, int* __restrict__ tile_m0,
                             int* __restrict__ tile_nrows, int* __restrict__ num_tiles) {
  __shared__ int cnt[EXP], off[EXP], cur[EXP];
  int tid = threadIdx.x;
  if (tid < EXP) { cnt[tid] = 0; cur[tid] = 0; }
  __syncthreads();
  for (int i = tid; i < NROWS; i += 256) atomicAdd(&cnt[sel_e[i]], 1);
  __syncthreads();
  if (tid == 0) {
    int running = 0, nt = 0;
    for (int e = 0; e < EXP; ++e) {
      off[e] = running;
      int c = cnt[e];
      int ntile = (c + BM - 1) / BM;
      for (int j = 0; j < ntile; ++j) {
        tile_e[nt] = e;
        tile_m0[nt] = running + j * BM;
        tile_nrows[nt] = min(BM, c - j * BM);
        ++nt;
      }
      running += c;
    }
    *num_tiles = nt;
  }
  __syncthreads();
  for (int i = tid; i < NROWS; i += 256) {
    int e = sel_e[i];
    int pos = off[e] + atomicAdd(&cur[e], 1);
    row_token[pos] = i >> 1;
    row_weight[pos] = sel_w[i];
  }
}

// ---------------- gather x rows -> contiguous bf16 A matrix ----------------
__global__ __launch_bounds__(256) void gather_kernel(const float* __restrict__ x,
                                                     const int* __restrict__ row_token,
                                                     u16* __restrict__ xg) {
  int r = blockIdx.x;
  int tok = row_token[r];
  const float4* xs = (const float4*)(x + (size_t)tok * HDIM);
  float4 v = xs[threadIdx.x];
  ushort4 o;
  o.x = f2bf(v.x); o.y = f2bf(v.y); o.z = f2bf(v.z); o.w = f2bf(v.w);
  *(ushort4*)(xg + (size_t)r * HDIM + threadIdx.x * 4) = o;
}

// -------- weight fp32 [E][R][C] -> bf16 [E][C][R] (B^T layout for GEMM) ----
__global__ __launch_bounds__(256) void transpose_convert(const float* __restrict__ src,
                                                         u16* __restrict__ dst, int R, int C) {
  int eb = blockIdx.z;
  const float* s = src + (size_t)eb * R * C;
  u16* d = dst + (size_t)eb * R * C;
  int cb = blockIdx.x * 64, rb = blockIdx.y * 64;
  __shared__ u16 tile[64][72];
  int tid = threadIdx.x;
#pragma unroll
  for (int i = 0; i < 4; ++i) {
    int idx = i * 256 + tid;
    int r = idx >> 4;
    int cq = (idx & 15) * 4;
    float4 v = *(const float4*)(s + (size_t)(rb + r) * C + cb + cq);
    tile[r][cq]     = f2bf(v.x);
    tile[r][cq + 1] = f2bf(v.y);
    tile[r][cq + 2] = f2bf(v.z);
    tile[r][cq + 3] = f2bf(v.w);
  }
  __syncthreads();
#pragma unroll
  for (int i = 0; i < 4; ++i) {
    int idx = i * 256 + tid;
    int c = idx >> 4;
    int rq = (idx & 15) * 4;
    ushort4 o;
    o.x = tile[rq][c]; o.y = tile[rq + 1][c]; o.z = tile[rq + 2][c]; o.w = tile[rq + 3][c];
    *(ushort4*)(d + (size_t)(cb + c) * R + rb + rq) = o;
  }
}

// ---------------- grouped GEMM (m97 structure), fused epilogues ------------
// A [rows][K] bf16 (expert-grouped rows), B [E][N][K] bf16 (pre-transposed).
// SECOND=false: hdn = silu(A@W1 + b1), bf16 store.
// SECOND=true : out[tok] += w * (A@W2 + b2), fp32 atomic scatter.
template <int K, bool SECOND>
__global__ __launch_bounds__(256, 2) void ffn_gemm(
    const u16* __restrict__ A, const u16* __restrict__ B,
    const float* __restrict__ bias, u16* __restrict__ hdn_out,
    float* __restrict__ out, const int* __restrict__ row_token,
    const float* __restrict__ row_weight, const int* __restrict__ tile_e,
    const int* __restrict__ tile_m0, const int* __restrict__ tile_nrows,
    const int* __restrict__ num_tiles, int N) {
  int ty = blockIdx.y;
  if (ty >= *num_tiles) return;
  int e = tile_e[ty];
  int row0 = tile_m0[ty];
  int nrows = tile_nrows[ty];
  int n0 = blockIdx.x * BN;

  __shared__ u16 sA[BM * BK];
  __shared__ u16 sB[BN * BK];

  int tid = threadIdx.x;
  int lane = tid & 63;
  int wave = tid >> 6;
  int wm = wave >> 1, wn = wave & 1;
  int l15 = lane & 15, quad = lane >> 4;

  const u16* Ab = A + (size_t)row0 * K;
  const u16* Bb = B + (size_t)e * (size_t)N * K + (size_t)n0 * K;

  const u16* pA[4]; const u16* pB[4];
  u16* dA[4]; u16* dB[4];
#pragma unroll
  for (int i = 0; i < 4; ++i) {
    int c = i * 256 + tid;            // 16B chunk id, lane-ordered for global_load_lds
    int row = c >> 3;
    int ko = (c & 7) * 8;
    pA[i] = Ab + (size_t)row * K + ko;
    pB[i] = Bb + (size_t)row * K + ko;
    dA[i] = sA + c * 8;
    dB[i] = sB + c * 8;
  }

  int aoff[4], boff[4];
#pragma unroll
  for (int i = 0; i < 4; ++i) {
    aoff[i] = (wm * 64 + i * 16 + l15) * BK + quad * 8;
    boff[i] = (wn * 64 + i * 16 + l15) * BK + quad * 8;
  }

  f32x4 acc[4][4];
#pragma unroll
  for (int am = 0; am < 4; ++am)
#pragma unroll
    for (int an = 0; an < 4; ++an) acc[am][an] = (f32x4){0.f, 0.f, 0.f, 0.f};

  for (int k0 = 0; k0 < K; k0 += BK) {
#pragma unroll
    for (int i = 0; i < 4; ++i) {
      async_copy16(pA[i] + k0, dA[i]);
      async_copy16(pB[i] + k0, dB[i]);
    }
    __syncthreads();
#pragma unroll
    for (int ks = 0; ks < 2; ++ks) {
      bf16x8 af[4], bfr[4];
#pragma unroll
      for (int i = 0; i < 4; ++i) af[i] = *(const bf16x8*)(sA + aoff[i] + ks * 32);
#pragma unroll
      for (int i = 0; i < 4; ++i) bfr[i] = *(const bf16x8*)(sB + boff[i] + ks * 32);
#pragma unroll
      for (int am = 0; am < 4; ++am)
#pragma unroll
        for (int an = 0; an < 4; ++an)
          acc[am][an] = __builtin_amdgcn_mfma_f32_16x16x32_bf16(af[am], bfr[an],
                                                               acc[am][an], 0, 0, 0);
    }
    __syncthreads();
  }

  if (!SECOND) {
#pragma unroll
    for (int an = 0; an < 4; ++an) {
      int col = n0 + wn * 64 + an * 16 + l15;
      float bv = bias[e * N + col];
#pragma unroll
      for (int am = 0; am < 4; ++am) {
#pragma unroll
        for (int r = 0; r < 4; ++r) {
          int lr = wm * 64 + am * 16 + quad * 4 + r;   // C/D: col=lane&15, row=quad*4+reg
          if (lr < nrows) {
            float vv = acc[am][an][r] + bv;
            vv = vv / (1.f + __expf(-vv));             // silu
            hdn_out[(size_t)(row0 + lr) * N + col] = f2bf(vv);
          }
        }
      }
    }
  } else {
    float bv[4];
#pragma unroll
    for (int an = 0; an < 4; ++an) bv[an] = bias[e * N + n0 + wn * 64 + an * 16 + l15];
#pragma unroll
    for (int am = 0; am < 4; ++am) {
#pragma unroll
      for (int r = 0; r < 4; ++r) {
        int lr = wm * 64 + am * 16 + quad * 4 + r;
        if (lr < nrows) {
          int grow = row0 + lr;
          int tok = row_token[grow];
          float w = row_weight[grow];
          float* orow = out + (size_t)tok * N;
#pragma unroll
          for (int an = 0; an < 4; ++an) {
            int col = n0 + wn * 64 + an * 16 + l15;
            atomicAdd(orow + col, (acc[am][an][r] + bv[an]) * w);
          }
        }
      }
    }
  }
}

extern "C" void kernel_launch(void* const* d_in, const int* in_sizes, int n_in,
                              void* d_out, int out_size, void* d_ws, size_t ws_size,
                              hipStream_t stream) {
  const float* x  = (const float*)d_in[0];
  const float* Wg = (const float*)d_in[1];
  const float* W1 = (const float*)d_in[2];
  const float* b1 = (const float*)d_in[3];
  const float* W2 = (const float*)d_in[4];
  const float* b2 = (const float*)d_in[5];
  float* out = (float*)d_out;

  char* ws = (char*)d_ws;
  size_t off = 0;
  auto alloc = [&](size_t bytes) {
    void* p = ws + off;
    off += (bytes + 255) & ~(size_t)255;
    return p;
  };
  u16* W1T = (u16*)alloc((size_t)EXP * IDIM * HDIM * 2);   // 67 MB  [E][I][H]
  u16* W2T = (u16*)alloc((size_t)EXP * IDIM * HDIM * 2);   // 67 MB  [E][H][I]
  u16* xg  = (u16*)alloc((size_t)PAD_ROWS * HDIM * 2);     // 17 MB
  u16* hdn = (u16*)alloc((size_t)PAD_ROWS * IDIM * 2);     // 68 MB
  int*   sel_e      = (int*)alloc(NROWS * 4);
  float* sel_w      = (float*)alloc(NROWS * 4);
  int*   row_token  = (int*)alloc(NROWS * 4);
  float* row_weight = (float*)alloc(NROWS * 4);
  int* tile_e     = (int*)alloc(MAX_TILES * 4);
  int* tile_m0    = (int*)alloc(MAX_TILES * 4);
  int* tile_nrows = (int*)alloc(MAX_TILES * 4);
  int* num_tiles  = (int*)alloc(4);

  hipMemsetAsync(d_out, 0, (size_t)out_size * sizeof(float), stream);
  transpose_convert<<<dim3(IDIM / 64, HDIM / 64, EXP), 256, 0, stream>>>(W1, W1T, HDIM, IDIM);
  transpose_convert<<<dim3(HDIM / 64, IDIM / 64, EXP), 256, 0, stream>>>(W2, W2T, IDIM, HDIM);
  gate_kernel<<<T_TOK / 4, 256, 0, stream>>>(x, Wg, sel_e, sel_w);
  route_kernel<<<1, 256, 0, stream>>>(sel_e, sel_w, row_token, row_weight,
                                      tile_e, tile_m0, tile_nrows, num_tiles);
  gather_kernel<<<NROWS, 256, 0, stream>>>(x, row_token, xg);
  ffn_gemm<HDIM, false><<<dim3(IDIM / BN, MAX_TILES), 256, 0, stream>>>(
      xg, W1T, b1, hdn, nullptr, nullptr, nullptr,
      tile_e, tile_m0, tile_nrows, num_tiles, IDIM);
  ffn_gemm<IDIM, true><<<dim3(HDIM / BN, MAX_TILES), 256, 0, stream>>>(
      hdn, W2T, b2, nullptr, out, row_token, row_weight,
      tile_e, tile_m0, tile_nrows, num_tiles, HDIM);
}

// Round 2
// 604.036 us; speedup vs baseline: 1.0456x; 1.0456x over previous
//
#include <hip/hip_runtime.h>
#include <cstdint>
#include <cstddef>

using u16 = unsigned short;
typedef __bf16 bf16x8 __attribute__((ext_vector_type(8)));
typedef float f32x4 __attribute__((ext_vector_type(4)));

#define T_TOK 4096
#define HDIM 1024
#define EXP 8
#define IDIM 4096
#define NROWS 8192      // T_TOK * 2, exact (top-2 always selects 2 distinct experts)
#define PAD_ROWS 8320   // +128 so last-tile OOB row reads stay inside ws
#define BM 128
#define BN 128
#define BK 64
#define MAX_TILES 72    // sum ceil(n_e/128) <= 64 + 7

__device__ __forceinline__ u16 f2bf(float f) {
  union { float f; uint32_t u; } v; v.f = f;
  uint32_t u = v.u;
  u += 0x7fffu + ((u >> 16) & 1u);   // RNE
  return (u16)(u >> 16);
}

__device__ __forceinline__ void async_copy16(const u16* g, u16* s) {
  __builtin_amdgcn_global_load_lds((__attribute__((address_space(1))) void*)(void*)g,
                                   (__attribute__((address_space(3))) void*)s, 16, 0, 0);
}

// ---------------- gating: fp32 logits, softmax/top-2/renorm -----------------
__global__ __launch_bounds__(256) void gate_kernel(const float* __restrict__ x,
                                                   const float* __restrict__ Wg,
                                                   int* __restrict__ sel_e,
                                                   float* __restrict__ sel_w) {
  int lane = threadIdx.x & 63;
  int wave = threadIdx.x >> 6;
  int t = blockIdx.x * 4 + wave;
  const float* xr = x + (size_t)t * HDIM;
  float p[8];
#pragma unroll
  for (int e = 0; e < 8; ++e) p[e] = 0.f;
#pragma unroll
  for (int i = 0; i < 16; ++i) {
    int h = i * 64 + lane;
    float xv = xr[h];
    const float4* w4 = (const float4*)(Wg + h * 8);
    float4 a = w4[0], b = w4[1];
    p[0] += xv * a.x; p[1] += xv * a.y; p[2] += xv * a.z; p[3] += xv * a.w;
    p[4] += xv * b.x; p[5] += xv * b.y; p[6] += xv * b.z; p[7] += xv * b.w;
  }
#pragma unroll
  for (int e = 0; e < 8; ++e) {
#pragma unroll
    for (int off = 32; off > 0; off >>= 1) p[e] += __shfl_xor(p[e], off);
  }
  if (lane == 0) {
    int e0 = 0; float m0 = p[0];
#pragma unroll
    for (int e = 1; e < 8; ++e) { if (p[e] > m0) { m0 = p[e]; e0 = e; } }
    int e1 = -1; float m1 = -3.4e38f;
#pragma unroll
    for (int e = 0; e < 8; ++e) { if (e != e0 && p[e] > m1) { m1 = p[e]; e1 = e; } }
    // renormalized top-2 softmax: denominator cancels
    float r = expf(m1 - m0);
    float w0 = 1.f / (1.f + r);
    float w1 = r / (1.f + r);
    sel_e[2 * t] = e0; sel_e[2 * t + 1] = e1;
    sel_w[2 * t] = w0; sel_w[2 * t + 1] = w1;
  }
}

// ---------------- routing: counting sort + tile descriptors -----------------
__global__ void route_kernel(const int* __restrict__ sel_e, const float* __restrict__ sel_w,
                             int* __restrict__ row_token, float* __restrict__ row_weight,
                             int* __restrict__ tile_e, int* __restrict__ tile_m0,
                             int* __restrict__ tile_nrows, int* __restrict__ num_tiles) {
  __shared__ int cnt[EXP], off[EXP], cur[EXP];
  int tid = threadIdx.x;
  if (tid < EXP) { cnt[tid] = 0; cur[tid] = 0; }
  __syncthreads();
  for (int i = tid; i < NROWS; i += 256) atomicAdd(&cnt[sel_e[i]], 1);
  __syncthreads();
  if (tid == 0) {
    int running = 0, nt = 0;
    for (int e = 0; e < EXP; ++e) {
      off[e] = running;
      int c = cnt[e];
      int ntile = (c + BM - 1) / BM;
      for (int j = 0; j < ntile; ++j) {
        tile_e[nt] = e;
        tile_m0[nt] = running + j * BM;
        tile_nrows[nt] = min(BM, c - j * BM);
        ++nt;
      }
      running += c;
    }
    *num_tiles = nt;
  }
  __syncthreads();
  for (int i = tid; i < NROWS; i += 256) {
    int e = sel_e[i];
    int pos = off[e] + atomicAdd(&cur[e], 1);
    row_token[pos] = i >> 1;
    row_weight[pos] = sel_w[i];
  }
}

// ---------------- gather x rows -> contiguous bf16 A matrix ----------------
__global__ __launch_bounds__(256) void gather_kernel(const float* __restrict__ x,
                                                     const int* __restrict__ row_token,
                                                     u16* __restrict__ xg) {
  int r = blockIdx.x;
  int tok = row_token[r];
  const float4* xs = (const float4*)(x + (size_t)tok * HDIM);
  float4 v = xs[threadIdx.x];
  ushort4 o;
  o.x = f2bf(v.x); o.y = f2bf(v.y); o.z = f2bf(v.z); o.w = f2bf(v.w);
  *(ushort4*)(xg + (size_t)r * HDIM + threadIdx.x * 4) = o;
}

// -------- weight fp32 [E][R][C] -> bf16 [E][C][R] (B^T layout for GEMM) ----
__global__ __launch_bounds__(256) void transpose_convert(const float* __restrict__ src,
                                                         u16* __restrict__ dst, int R, int C) {
  int eb = blockIdx.z;
  const float* s = src + (size_t)eb * R * C;
  u16* d = dst + (size_t)eb * R * C;
  int cb = blockIdx.x * 64, rb = blockIdx.y * 64;
  __shared__ u16 tile[64][72];
  int tid = threadIdx.x;
#pragma unroll
  for (int i = 0; i < 4; ++i) {
    int idx = i * 256 + tid;
    int r = idx >> 4;
    int cq = (idx & 15) * 4;
    float4 v = *(const float4*)(s + (size_t)(rb + r) * C + cb + cq);
    tile[r][cq]     = f2bf(v.x);
    tile[r][cq + 1] = f2bf(v.y);
    tile[r][cq + 2] = f2bf(v.z);
    tile[r][cq + 3] = f2bf(v.w);
  }
  __syncthreads();
#pragma unroll
  for (int i = 0; i < 4; ++i) {
    int idx = i * 256 + tid;
    int c = idx >> 4;
    int rq = (idx & 15) * 4;
    ushort4 o;
    o.x = tile[rq][c]; o.y = tile[rq + 1][c]; o.z = tile[rq + 2][c]; o.w = tile[rq + 3][c];
    *(ushort4*)(d + (size_t)(cb + c) * R + rb + rq) = o;
  }
}

// ---------------- grouped GEMM (m97 structure), fused epilogues ------------
// A [rows][K] bf16 (expert-grouped rows), B [E][N][K] bf16 (pre-transposed).
// LDS layout is XOR-swizzled: 16B chunk (row, j) of a tile lives at slot
// row*8 + (j ^ (row&7)). global_load_lds keeps its lane-linear LDS dest; each
// lane instead fetches the permuted global chunk (same 128B row per 8 lanes,
// so global coalescing is unchanged). Fragment reads then hit all 32 banks
// with 2-way aliasing only (free) instead of the 16-way row-stride conflict.
// SECOND=false: hdn = silu(A@W1 + b1), bf16 store.
// SECOND=true : out[tok] += w * (A@W2 + b2), fp32 atomic scatter.
template <int K, bool SECOND>
__global__ __launch_bounds__(256, 2) void ffn_gemm(
    const u16* __restrict__ A, const u16* __restrict__ B,
    const float* __restrict__ bias, u16* __restrict__ hdn_out,
    float* __restrict__ out, const int* __restrict__ row_token,
    const float* __restrict__ row_weight, const int* __restrict__ tile_e,
    const int* __restrict__ tile_m0, const int* __restrict__ tile_nrows,
    const int* __restrict__ num_tiles, int N) {
  int ty = blockIdx.y;
  if (ty >= *num_tiles) return;
  int e = tile_e[ty];
  int row0 = tile_m0[ty];
  int nrows = tile_nrows[ty];
  int n0 = blockIdx.x * BN;

  __shared__ u16 sA[BM * BK];
  __shared__ u16 sB[BN * BK];

  int tid = threadIdx.x;
  int lane = tid & 63;
  int wave = tid >> 6;
  int wm = wave >> 1, wn = wave & 1;
  int l15 = lane & 15, quad = lane >> 4;
  int r7 = l15 & 7;

  const u16* Ab = A + (size_t)row0 * K;
  const u16* Bb = B + (size_t)e * (size_t)N * K + (size_t)n0 * K;

  const u16* pA[4]; const u16* pB[4];
  u16* dA[4]; u16* dB[4];
#pragma unroll
  for (int i = 0; i < 4; ++i) {
    int c = i * 256 + tid;            // LDS slot id (lane-ordered for global_load_lds)
    int row = c >> 3;
    int j = (c & 7) ^ (row & 7);      // global chunk this slot holds (XOR swizzle)
    pA[i] = Ab + (size_t)row * K + j * 8;
    pB[i] = Bb + (size_t)row * K + j * 8;
    dA[i] = sA + c * 8;
    dB[i] = sB + c * 8;
  }

  // fragment row = wm*64 + i*16 + l15  ->  row&7 == l15&7, independent of i.
  int abase[4], bbase[4];
#pragma unroll
  for (int i = 0; i < 4; ++i) {
    abase[i] = (wm * 64 + i * 16 + l15) * BK;
    bbase[i] = (wn * 64 + i * 16 + l15) * BK;
  }
  int jx[2];
#pragma unroll
  for (int ks = 0; ks < 2; ++ks) jx[ks] = ((ks * 4 + quad) ^ r7) * 8;

  f32x4 acc[4][4];
#pragma unroll
  for (int am = 0; am < 4; ++am)
#pragma unroll
    for (int an = 0; an < 4; ++an) acc[am][an] = (f32x4){0.f, 0.f, 0.f, 0.f};

  for (int k0 = 0; k0 < K; k0 += BK) {
#pragma unroll
    for (int i = 0; i < 4; ++i) {
      async_copy16(pA[i] + k0, dA[i]);
      async_copy16(pB[i] + k0, dB[i]);
    }
    __syncthreads();
#pragma unroll
    for (int ks = 0; ks < 2; ++ks) {
      bf16x8 af[4], bfr[4];
#pragma unroll
      for (int i = 0; i < 4; ++i) af[i] = *(const bf16x8*)(sA + abase[i] + jx[ks]);
#pragma unroll
      for (int i = 0; i < 4; ++i) bfr[i] = *(const bf16x8*)(sB + bbase[i] + jx[ks]);
#pragma unroll
      for (int am = 0; am < 4; ++am)
#pragma unroll
        for (int an = 0; an < 4; ++an)
          acc[am][an] = __builtin_amdgcn_mfma_f32_16x16x32_bf16(af[am], bfr[an],
                                                               acc[am][an], 0, 0, 0);
    }
    __syncthreads();
  }

  if (!SECOND) {
#pragma unroll
    for (int an = 0; an < 4; ++an) {
      int col = n0 + wn * 64 + an * 16 + l15;
      float bv = bias[e * N + col];
#pragma unroll
      for (int am = 0; am < 4; ++am) {
#pragma unroll
        for (int r = 0; r < 4; ++r) {
          int lr = wm * 64 + am * 16 + quad * 4 + r;   // C/D: col=lane&15, row=quad*4+reg
          if (lr < nrows) {
            float vv = acc[am][an][r] + bv;
            vv = vv / (1.f + __expf(-vv));             // silu
            hdn_out[(size_t)(row0 + lr) * N + col] = f2bf(vv);
          }
        }
      }
    }
  } else {
    float bv[4];
#pragma unroll
    for (int an = 0; an < 4; ++an) bv[an] = bias[e * N + n0 + wn * 64 + an * 16 + l15];
#pragma unroll
    for (int am = 0; am < 4; ++am) {
#pragma unroll
      for (int r = 0; r < 4; ++r) {
        int lr = wm * 64 + am * 16 + quad * 4 + r;
        if (lr < nrows) {
          int grow = row0 + lr;
          int tok = row_token[grow];
          float w = row_weight[grow];
          float* orow = out + (size_t)tok * N;
#pragma unroll
          for (int an = 0; an < 4; ++an) {
            int col = n0 + wn * 64 + an * 16 + l15;
            atomicAdd(orow + col, (acc[am][an][r] + bv[an]) * w);
          }
        }
      }
    }
  }
}

extern "C" void kernel_launch(void* const* d_in, const int* in_sizes, int n_in,
                              void* d_out, int out_size, void* d_ws, size_t ws_size,
                              hipStream_t stream) {
  const float* x  = (const float*)d_in[0];
  const float* Wg = (const float*)d_in[1];
  const float* W1 = (const float*)d_in[2];
  const float* b1 = (const float*)d_in[3];
  const float* W2 = (const float*)d_in[4];
  const float* b2 = (const float*)d_in[5];
  float* out = (float*)d_out;

  char* ws = (char*)d_ws;
  size_t off = 0;
  auto alloc = [&](size_t bytes) {
    void* p = ws + off;
    off += (bytes + 255) & ~(size_t)255;
    return p;
  };
  u16* W1T = (u16*)alloc((size_t)EXP * IDIM * HDIM * 2);   // 67 MB  [E][I][H]
  u16* W2T = (u16*)alloc((size_t)EXP * IDIM * HDIM * 2);   // 67 MB  [E][H][I]
  u16* xg  = (u16*)alloc((size_t)PAD_ROWS * HDIM * 2);     // 17 MB
  u16* hdn = (u16*)alloc((size_t)PAD_ROWS * IDIM * 2);     // 68 MB
  int*   sel_e      = (int*)alloc(NROWS * 4);
  float* sel_w      = (float*)alloc(NROWS * 4);
  int*   row_token  = (int*)alloc(NROWS * 4);
  float* row_weight = (float*)alloc(NROWS * 4);
  int* tile_e     = (int*)alloc(MAX_TILES * 4);
  int* tile_m0    = (int*)alloc(MAX_TILES * 4);
  int* tile_nrows = (int*)alloc(MAX_TILES * 4);
  int* num_tiles  = (int*)alloc(4);

  hipMemsetAsync(d_out, 0, (size_t)out_size * sizeof(float), stream);
  transpose_convert<<<dim3(IDIM / 64, HDIM / 64, EXP), 256, 0, stream>>>(W1, W1T, HDIM, IDIM);
  transpose_convert<<<dim3(HDIM / 64, IDIM / 64, EXP), 256, 0, stream>>>(W2, W2T, IDIM, HDIM);
  gate_kernel<<<T_TOK / 4, 256, 0, stream>>>(x, Wg, sel_e, sel_w);
  route_kernel<<<1, 256, 0, stream>>>(sel_e, sel_w, row_token, row_weight,
                                      tile_e, tile_m0, tile_nrows, num_tiles);
  gather_kernel<<<NROWS, 256, 0, stream>>>(x, row_token, xg);
  ffn_gemm<HDIM, false><<<dim3(IDIM / BN, MAX_TILES), 256, 0, stream>>>(
      xg, W1T, b1, hdn, nullptr, nullptr, nullptr,
      tile_e, tile_m0, tile_nrows, num_tiles, IDIM);
  ffn_gemm<IDIM, true><<<dim3(HDIM / BN, MAX_TILES), 256, 0, stream>>>(
      hdn, W2T, b2, nullptr, out, row_token, row_weight,
      tile_e, tile_m0, tile_nrows, num_tiles, HDIM);
}